// Round 10
// baseline (364.605 us; speedup 1.0000x reference)
//
#include <hip/hip_runtime.h>

#define NN 50000
#define EE 800000
#define GG 512
#define TILES 782          // ceil(NN/64)
#define CSRB 1024          // blocks in persistent CSR kernel: 4/CU vs 8/CU cap

typedef __attribute__((ext_vector_type(8))) short short8;
typedef __attribute__((ext_vector_type(4))) float f32x4;

__device__ __forceinline__ float b2f(unsigned short u) {
    union { unsigned int i; float f; } c;
    c.i = ((unsigned int)u) << 16;
    return c.f;
}
__device__ __forceinline__ unsigned short f2b(float f) {
    union { float f; unsigned int i; } c;
    c.f = f;
    const unsigned int r = c.i + 0x7FFFu + ((c.i >> 16) & 1u);  // rne
    return (unsigned short)(r >> 16);
}
__device__ __forceinline__ int rfl(int v) { return __builtin_amdgcn_readfirstlane(v); }

__device__ __forceinline__ int lowb(const int* b, int v) {
    int lo = 0, hi = NN;
    while (lo < hi) { const int m = (lo + hi) >> 1; if (b[m] < v) lo = m + 1; else hi = m; }
    return lo;
}

// ===========================================================================
// prep: x fp32->bf16, zero counts/ctrl/stats/xpool, weight swizzle (last 6
// blocks).
// ===========================================================================
__global__ __launch_bounds__(256) void prep_kernel(const float* __restrict__ x,
                                                   unsigned short* __restrict__ xbf,
                                                   int* __restrict__ counts,
                                                   int* __restrict__ ctrl,
                                                   float* __restrict__ zblock,
                                                   const float* __restrict__ w0,
                                                   const float* __restrict__ w1,
                                                   const float* __restrict__ w2,
                                                   const float* __restrict__ w3,
                                                   const float* __restrict__ w4,
                                                   const float* __restrict__ w5,
                                                   unsigned short* __restrict__ wfrag) {
    if (blockIdx.x >= 3210) {   // weight swizzle: fp32 [k][n] -> B-frag order
        const float* ws[6] = {w0, w1, w2, w3, w4, w5};
        const int wi = blockIdx.x - 3210;
        const float* w = ws[wi];
        unsigned short* o = wfrag + wi * 4096;
        #pragma unroll
        for (int it = 0; it < 2; ++it) {
            const int idx = it * 256 + threadIdx.x;
            const int fid = idx >> 6, lane = idx & 63;
            const int kt = fid >> 2, nt = fid & 3;
            const int kbase = kt * 32 + (lane >> 4) * 8;
            const int n = nt * 16 + (lane & 15);
            #pragma unroll
            for (int j = 0; j < 8; ++j)
                o[idx * 8 + j] = f2b(w[(kbase + j) * 64 + n]);
        }
        return;
    }
    const int tid = blockIdx.x * 256 + threadIdx.x;
    if (tid < 800000) {
        const float4 v = ((const float4*)x)[tid];
        ushort4 o;
        o.x = f2b(v.x); o.y = f2b(v.y); o.z = f2b(v.z); o.w = f2b(v.w);
        ((ushort4*)xbf)[tid] = o;
    } else if (tid < 812500) {
        ((int4*)counts)[tid - 800000] = make_int4(0, 0, 0, 0);
    } else if (tid < 812756) {
        ((int4*)ctrl)[tid - 812500] = make_int4(0, 0, 0, 0);
    } else if (tid < 821716) {   // stats (3072) + xpool (32768) floats
        ((float4*)zblock)[tid - 812756] = make_float4(0.f, 0.f, 0.f, 0.f);
    }
}

// ===========================================================================
// Persistent CSR build: hist -> alloc (order-free wave-scan) -> fill, one
// kernel, 1024 blocks (4/CU vs 8/CU occupancy cap -> co-residency margin),
// two FLAT fence-free barriers (all cross-phase state is fabric-atomic; bulk
// outputs read only after kernel end). Round-9 lesson: 256 blocks starved
// the latency-bound hist/fill (155us); parallelism, not barriers, was the cost.
// ===========================================================================
__global__ __launch_bounds__(256, 4) void csr_kernel(const int* __restrict__ ei,
                                                     int* __restrict__ counts,
                                                     int* __restrict__ rowbeg,
                                                     int* __restrict__ cursor,
                                                     int* __restrict__ ctrl,
                                                     int* __restrict__ col) {
    const int gtid = blockIdx.x * 256 + threadIdx.x;
    const int lane = threadIdx.x & 63;

#define CBAR(slot) do {                                                        \
        __syncthreads();                                                       \
        if (threadIdx.x == 0) {                                                \
            __hip_atomic_fetch_add(&ctrl[slot], 1, __ATOMIC_RELAXED,           \
                                   __HIP_MEMORY_SCOPE_AGENT);                  \
            int sp = 0;                                                        \
            while (__hip_atomic_load(&ctrl[slot], __ATOMIC_RELAXED,            \
                                     __HIP_MEMORY_SCOPE_AGENT) < CSRB) {       \
                __builtin_amdgcn_s_sleep(2);                                   \
                if (++sp > (1 << 20)) break;                                   \
            }                                                                  \
        }                                                                      \
        __syncthreads();                                                       \
    } while (0)

    // ---- A: histogram (fabric RMW), ~3 edges/thread ----
    for (int e = gtid; e < EE; e += CSRB * 256) atomicAdd(&counts[ei[EE + e]], 1);
    CBAR(128);

    // ---- B: alloc (order-free rowbeg; wave scan + one atomic per wave) ----
    {
        const int gw = gtid >> 6;
        if (gw < TILES) {
            const int r = gw * 64 + lane;
            const int cnt = (r < NN) ? counts[r] : 0;   // normal read post-final
            int incl = cnt;
            #pragma unroll
            for (int off = 1; off < 64; off <<= 1) {
                const int tv = __shfl_up(incl, off);
                if (lane >= off) incl += tv;
            }
            const int tot = __shfl(incl, 63);
            int base = 0;
            if (lane == 63)
                base = __hip_atomic_fetch_add(&ctrl[64], tot, __ATOMIC_RELAXED,
                                              __HIP_MEMORY_SCOPE_AGENT);
            base = __shfl(base, 63);
            if (r < NN) {
                const int b0 = base + incl - cnt;
                rowbeg[r] = b0;                           // read after kernel end
                __hip_atomic_store(&cursor[r], b0, __ATOMIC_RELAXED,
                                   __HIP_MEMORY_SCOPE_AGENT);   // fabric (C RMWs it)
            }
        }
    }
    CBAR(160);

    // ---- C: fill (8 classes x 128 chunk-blocks, 6250 edges/block) ----
    {
        const int cls = blockIdx.x & 7;
        for (int e = (blockIdx.x >> 3) * 256 + threadIdx.x; e < EE; e += 128 * 256) {
            const int dst = ei[EE + e];
            if (dst / 6250 == cls) {
                const int pos = atomicAdd(&cursor[dst], 1);
                col[pos] = ei[e];
            }
        }
    }
#undef CBAR
}

// ===========================================================================
// Gather (round-0 proven): one wave per row, deg-adaptive batches, previous
// layer's BN finalize folded. z = scl.*(h_self + sum_nbr h) + (deg+1).*sft
// ===========================================================================
__global__ __launch_bounds__(256, 4) void gather_kernel(const unsigned short* __restrict__ hin,
                                                        const int* __restrict__ rowbeg,
                                                        const int* __restrict__ counts,
                                                        const int* __restrict__ col,
                                                        const float* __restrict__ stats,
                                                        const float* __restrict__ ga,
                                                        const float* __restrict__ be,
                                                        const int apply,
                                                        unsigned short* __restrict__ z) {
    const int wv = (blockIdx.x * 256 + threadIdx.x) >> 6;
    const int lane = threadIdx.x & 63;
    const int row = rfl(wv);
    if (row >= NN) return;

    float scl = 1.0f, sft = 0.0f;
    if (apply) {
        float s = 0.f, sq = 0.f;
        #pragma unroll
        for (int k = 0; k < 8; ++k) {
            s += stats[k * 128 + lane];
            sq += stats[k * 128 + 64 + lane];
        }
        const float mean = s * (1.0f / NN);
        const float var = sq * (1.0f / NN) - mean * mean;
        scl = ga[lane] * rsqrtf(var + 1e-5f);
        sft = be[lane] - mean * scl;
    }

    const int beg = rfl(rowbeg[row]);
    const int deg = rfl(counts[row]);
    const int end = beg + deg;
    float a[8];
    #pragma unroll
    for (int i = 0; i < 8; ++i) a[i] = 0.f;
    a[0] = b2f(hin[row * 64 + lane]);   // self term

    if (deg <= 16) {
        const int safeb = (beg < EE) ? beg : 0;
        int c[16];
        #pragma unroll
        for (int i = 0; i < 16; ++i) {
            const int jj = (i < deg) ? (beg + i) : safeb;
            c[i] = rfl(col[jj]);
        }
        float hv[16];
        #pragma unroll
        for (int i = 0; i < 16; ++i) hv[i] = b2f(hin[c[i] * 64 + lane]);
        #pragma unroll
        for (int i = 0; i < 16; ++i) a[i & 7] += (i < deg) ? hv[i] : 0.f;
    } else if (deg <= 24) {
        int c[24];
        #pragma unroll
        for (int i = 0; i < 24; ++i) {
            const int jj = (i < deg) ? (beg + i) : beg;
            c[i] = rfl(col[jj]);
        }
        float hv[24];
        #pragma unroll
        for (int i = 0; i < 24; ++i) hv[i] = b2f(hin[c[i] * 64 + lane]);
        #pragma unroll
        for (int i = 0; i < 24; ++i) a[i & 7] += (i < deg) ? hv[i] : 0.f;
    } else if (deg <= 32) {
        int c[32];
        #pragma unroll
        for (int i = 0; i < 32; ++i) {
            const int jj = (i < deg) ? (beg + i) : beg;
            c[i] = rfl(col[jj]);
        }
        float hv[32];
        #pragma unroll
        for (int i = 0; i < 32; ++i) hv[i] = b2f(hin[c[i] * 64 + lane]);
        #pragma unroll
        for (int i = 0; i < 32; ++i) a[i & 7] += (i < deg) ? hv[i] : 0.f;
    } else {
        int j = beg;
        for (; j + 16 <= end; j += 16) {
            int c[16];
            #pragma unroll
            for (int i = 0; i < 16; ++i) c[i] = rfl(col[j + i]);
            float hv[16];
            #pragma unroll
            for (int i = 0; i < 16; ++i) hv[i] = b2f(hin[c[i] * 64 + lane]);
            #pragma unroll
            for (int i = 0; i < 16; ++i) a[i & 7] += hv[i];
        }
        if (j < end) {
            int c[16];
            #pragma unroll
            for (int i = 0; i < 16; ++i) {
                const int jj = (j + i < end) ? (j + i) : beg;
                c[i] = rfl(col[jj]);
            }
            float hv[16];
            #pragma unroll
            for (int i = 0; i < 16; ++i) hv[i] = b2f(hin[c[i] * 64 + lane]);
            #pragma unroll
            for (int i = 0; i < 16; ++i) a[i & 7] += (j + i < end) ? hv[i] : 0.f;
        }
    }
    const float sum = ((a[0] + a[1]) + (a[2] + a[3])) + ((a[4] + a[5]) + (a[6] + a[7]));
    z[row * 64 + lane] = f2b(fmaf(sum, scl, (float)(deg + 1) * sft));
}

// ===========================================================================
// MFMA MLP (round-0 proven, reg-weights, (256,2)). dopool: instead of
// writing tout, accumulate RAW per-graph sums into xpool (BN3 finalize is
// affine -> applied in head: sum(bn(t)) = scl*sum(t) + cnt*sft).
// ===========================================================================
__global__ __launch_bounds__(256, 2) void mlp_kernel(const unsigned short* __restrict__ z,
                                                     const unsigned short* __restrict__ wfa,
                                                     const float* __restrict__ ba,
                                                     const unsigned short* __restrict__ wfb,
                                                     const float* __restrict__ bb,
                                                     unsigned short* __restrict__ tout,
                                                     float* __restrict__ stats,
                                                     const int* __restrict__ batch,
                                                     float* __restrict__ xpool,
                                                     const int dopool) {
    __shared__ unsigned short ldsT[4][16][72];
    __shared__ float red[512];

    const int wave = threadIdx.x >> 6;
    const int lane = threadIdx.x & 63;
    const int quad = lane >> 4;
    const int l15 = lane & 15;
    const int rowbase = blockIdx.x * 64 + wave * 16;
    const bool valid = rowbase < NN;

    short8 wA[8], wB[8];
    #pragma unroll
    for (int f = 0; f < 8; ++f) {
        wA[f] = *(const short8*)(wfa + (f * 64 + lane) * 8);
        wB[f] = *(const short8*)(wfb + (f * 64 + lane) * 8);
    }
    float biasA[4], biasB[4];
    #pragma unroll
    for (int nt = 0; nt < 4; ++nt) {
        biasA[nt] = ba[nt * 16 + l15];
        biasB[nt] = bb[nt * 16 + l15];
    }

    const int arow = valid ? (rowbase + l15) : 0;
    const short8 a0 = *(const short8*)(z + arow * 64 + quad * 8);
    const short8 a1 = *(const short8*)(z + arow * 64 + 32 + quad * 8);

    f32x4 acc[4];
    #pragma unroll
    for (int nt = 0; nt < 4; ++nt) {
        f32x4 c = {0.f, 0.f, 0.f, 0.f};
        c = __builtin_amdgcn_mfma_f32_16x16x32_bf16(a0, wA[nt], c, 0, 0, 0);
        c = __builtin_amdgcn_mfma_f32_16x16x32_bf16(a1, wA[4 + nt], c, 0, 0, 0);
        acc[nt] = c;
    }
    #pragma unroll
    for (int nt = 0; nt < 4; ++nt)
        #pragma unroll
        for (int r = 0; r < 4; ++r)
            ldsT[wave][quad * 4 + r][nt * 16 + l15] =
                f2b(fmaxf(acc[nt][r] + biasA[nt], 0.f));

    const short8 y0 = *(const short8*)(&ldsT[wave][l15][quad * 8]);
    const short8 y1 = *(const short8*)(&ldsT[wave][l15][32 + quad * 8]);

    #pragma unroll
    for (int nt = 0; nt < 4; ++nt) {
        f32x4 c = {0.f, 0.f, 0.f, 0.f};
        c = __builtin_amdgcn_mfma_f32_16x16x32_bf16(y0, wB[nt], c, 0, 0, 0);
        c = __builtin_amdgcn_mfma_f32_16x16x32_bf16(y1, wB[4 + nt], c, 0, 0, 0);
        acc[nt] = c;
    }
    #pragma unroll
    for (int nt = 0; nt < 4; ++nt)
        #pragma unroll
        for (int r = 0; r < 4; ++r)
            ldsT[wave][quad * 4 + r][nt * 16 + l15] =
                f2b(fmaxf(acc[nt][r] + biasB[nt], 0.f));

    // BN partials (wave reads its own region; same-wave ordered)
    {
        float s = 0.f, sq = 0.f;
        if (valid) {
            #pragma unroll 4
            for (int r = 0; r < 16; ++r) {
                const float v = b2f(ldsT[wave][r][lane]);
                s += v;
                sq += v * v;
            }
        }
        red[wave * 128 + lane] = s;
        red[wave * 128 + 64 + lane] = sq;
    }
    __syncthreads();

    if (threadIdx.x < 128) {
        const float tot = red[threadIdx.x] + red[128 + threadIdx.x] +
                          red[256 + threadIdx.x] + red[384 + threadIdx.x];
        atomicAdd(&stats[(blockIdx.x & 7) * 128 + threadIdx.x], tot);
    }

    if (!dopool) {
        #pragma unroll
        for (int m = 0; m < 4; ++m) {
            const int g = m * 256 + threadIdx.x;
            const int r = g >> 4;
            const int f4 = (g & 15) * 4;
            const int grow = blockIdx.x * 64 + r;
            if (grow < NN)
                *(ushort4*)(tout + grow * 64 + f4) =
                    *(const ushort4*)(&ldsT[r >> 4][r & 15][f4]);
        }
    } else if (valid) {
        // folded pool: raw (pre-BN) per-graph sums (batch sorted)
        int gprev = rfl(batch[rowbase]);
        float acc2 = 0.f;
        for (int i = 0; i < 16; ++i) {
            const int row = rowbase + i;
            if (row >= NN) break;
            const int g = rfl(batch[row]);
            const float v = b2f(ldsT[wave][i][lane]);
            if (g != gprev) {
                atomicAdd(&xpool[gprev * 64 + lane], acc2);
                acc2 = 0.f;
                gprev = g;
            }
            acc2 += v;
        }
        atomicAdd(&xpool[gprev * 64 + lane], acc2);
    }
}

// ===========================================================================
// Head: BN3 finalize (raw xpool + cnt*sft via binary search) + 2-layer MLP.
// ===========================================================================
__global__ __launch_bounds__(128) void head_kernel(const float* __restrict__ xpool,
                                                   const int* __restrict__ batch,
                                                   const float* __restrict__ stats,
                                                   const float* __restrict__ g3,
                                                   const float* __restrict__ be3,
                                                   const float* __restrict__ w0,
                                                   const float* __restrict__ b0,
                                                   const float* __restrict__ w1,
                                                   const float* __restrict__ b1,
                                                   float* __restrict__ out) {
    __shared__ float xp[64];
    __shared__ float midl[128];
    const int g = blockIdx.x;
    const int t = threadIdx.x;
    if (t < 64) {
        float s = 0.f, sq = 0.f;
        #pragma unroll
        for (int k = 0; k < 8; ++k) {
            s += stats[k * 128 + t];
            sq += stats[k * 128 + 64 + t];
        }
        const float mean = s * (1.0f / NN);
        const float var = sq * (1.0f / NN) - mean * mean;
        const float scl = g3[t] * rsqrtf(var + 1e-5f);
        const float sft = be3[t] - mean * scl;
        const int cnt = lowb(batch, g + 1) - lowb(batch, g);
        xp[t] = fmaf(xpool[g * 64 + t], scl, (float)cnt * sft);
    }
    __syncthreads();
    float acc = b0[t];
    #pragma unroll 8
    for (int k = 0; k < 64; ++k) acc = fmaf(xp[k], w0[k * 128 + t], acc);
    midl[t] = acc;
    __syncthreads();
    if (t < 64) {
        float a2 = b1[t];
        #pragma unroll 8
        for (int k = 0; k < 128; ++k) a2 = fmaf(midl[k], w1[k * 64 + t], a2);
        out[g * 64 + t] = fmaxf(a2, 0.f);
    }
}

extern "C" void kernel_launch(void* const* d_in, const int* in_sizes, int n_in,
                              void* d_out, int out_size, void* d_ws, size_t ws_size,
                              hipStream_t stream) {
    const float* x = (const float*)d_in[0];
    const int* ei = (const int*)d_in[1];
    const int* batch = (const int*)d_in[2];

    // ---- workspace layout ----
    int* ibase   = (int*)d_ws;
    int* counts  = ibase;            // 50000
    int* rowbeg  = ibase + 50000;    // 50000
    int* cursor  = ibase + 100000;   // 50000
    int* ctrl    = ibase + 150000;   // 1024 (zeroed by prep)
    int* col     = ibase + 151040;   // 800000 -> end 951040
    float* fbase = (float*)d_ws + 951040;
    float* stats = fbase;            // 3 x 1024
    float* xpool = stats + 3072;     // 32768 (raw pre-BN sums)
    unsigned short* zbf   = (unsigned short*)(fbase + 35840);  // NN*64
    unsigned short* xbf   = zbf + 3200000;
    unsigned short* t0bf  = xbf + 3200000;
    unsigned short* t1bf  = t0bf + 3200000;
    unsigned short* wfrag = t1bf + 3200000;      // 6 x 4096 bf16

    prep_kernel<<<3216, 256, 0, stream>>>(x, xbf, counts, ctrl, stats,
                                          (const float*)d_in[3], (const float*)d_in[5],
                                          (const float*)d_in[9], (const float*)d_in[11],
                                          (const float*)d_in[15], (const float*)d_in[17],
                                          wfrag);
    csr_kernel<<<CSRB, 256, 0, stream>>>(ei, counts, rowbeg, cursor, ctrl, col);

    const unsigned short* hcur = xbf;
    unsigned short* touts[3] = {t0bf, t1bf, t0bf};
    for (int l = 0; l < 3; ++l) {
        const float* ba = (const float*)d_in[3 + l * 6 + 1];
        const float* bb = (const float*)d_in[3 + l * 6 + 3];
        const float* gp = (const float*)d_in[3 + (l ? (l - 1) : 0) * 6 + 4];
        const float* bp = (const float*)d_in[3 + (l ? (l - 1) : 0) * 6 + 5];

        gather_kernel<<<12500, 256, 0, stream>>>(hcur, rowbeg, counts, col,
                                                 stats + (l ? (l - 1) : 0) * 1024,
                                                 gp, bp, l > 0, zbf);
        mlp_kernel<<<TILES, 256, 0, stream>>>(zbf,
                                              wfrag + (l * 2 + 0) * 4096, ba,
                                              wfrag + (l * 2 + 1) * 4096, bb,
                                              touts[l], stats + l * 1024,
                                              batch, xpool, (l == 2) ? 1 : 0);
        hcur = touts[l];
    }

    head_kernel<<<GG, 128, 0, stream>>>(
        xpool, batch, stats + 2048,
        (const float*)d_in[19], (const float*)d_in[20],
        (const float*)d_in[21], (const float*)d_in[22],
        (const float*)d_in[23], (const float*)d_in[24], (float*)d_out);
}